// Round 7
// baseline (5622.932 us; speedup 1.0000x reference)
//
#include <hip/hip_runtime.h>
#include <math.h>

#define BATCH 16
#define TLEN 2048
#define NTOK (BATCH*TLEN)       // 32768
#define DMODEL 160
#define DINNER 320
#define DSTATE 64
#define DTRANK 10
#define XDBL 138                // DTRANK + 2*D_STATE
#define DCONV 12
#define PREK 9
#define NBLK 8
#define NPART 8
#define PT (TLEN/NPART)         // 256

typedef __attribute__((ext_vector_type(8))) short short8;
typedef __attribute__((ext_vector_type(4))) float floatx4;

__device__ __forceinline__ float sigmoidf_(float x) { return 1.f / (1.f + __expf(-x)); }
__device__ __forceinline__ unsigned short f2bf(float f) {
  union { float f; unsigned u; } v; v.f = f;
  unsigned r = v.u + 0x7FFF + ((v.u >> 16) & 1);   // round-to-nearest-even
  return (unsigned short)(r >> 16);
}
__device__ __forceinline__ float bf2f(unsigned short s) {
  union { unsigned u; float f; } v; v.u = ((unsigned)s) << 16;
  return v.f;
}

// ---------------- pre conv (k=9, same pad) + exact GELU ----------------
__global__ __launch_bounds__(256)
void k_preconv(const float* __restrict__ x, const float* __restrict__ w,
               const float* __restrict__ bias, float* __restrict__ h) {
  int gid = blockIdx.x * 256 + threadIdx.x;
  if (gid >= NTOK * DMODEL) return;
  int c = gid % DMODEL;
  int tok = gid / DMODEL;
  int b = tok / TLEN, t = tok % TLEN;
  const float* xb = x + (size_t)b * TLEN;
  float acc = bias[c];
#pragma unroll
  for (int k = 0; k < PREK; ++k) {
    int tp = t + k - PREK / 2;
    float xv = (tp >= 0 && tp < TLEN) ? xb[tp] : 0.f;
    acc = fmaf(w[c * PREK + k], xv, acc);
  }
  h[gid] = 0.5f * acc * (1.f + erff(acc * 0.70710678118654752440f));
}

// ---------------- per-layer weight cast to bf16 ----------------
__global__ __launch_bounds__(256)
void k_cast(const float* __restrict__ iw, const float* __restrict__ xw,
            const float* __restrict__ ow, unsigned short* __restrict__ wbf) {
  int i = blockIdx.x * 256 + threadIdx.x;
  if (i < 102400) wbf[i] = f2bf(iw[i]);
  else if (i < 146560) wbf[i] = f2bf(xw[i - 102400]);
  else if (i < 197760) wbf[i] = f2bf(ow[i - 146560]);
}

// ---------------- LayerNorm over d=160 -> bf16 out ----------------
__global__ __launch_bounds__(256)
void k_ln(const float* __restrict__ h, const float* __restrict__ g,
          const float* __restrict__ bb, unsigned short* __restrict__ y) {
  int row = blockIdx.x * 4 + (threadIdx.x >> 6);
  int lane = threadIdx.x & 63;
  const float* hr = h + (size_t)row * DMODEL;
  float v0 = hr[lane], v1 = hr[lane + 64];
  float v2 = (lane < DMODEL - 128) ? hr[lane + 128] : 0.f;
  float s = v0 + v1 + v2;
  float sq = v0 * v0 + v1 * v1 + v2 * v2;
#pragma unroll
  for (int off = 32; off; off >>= 1) {
    s += __shfl_xor(s, off);
    sq += __shfl_xor(sq, off);
  }
  float mean = s * (1.f / DMODEL);
  float var = sq * (1.f / DMODEL) - mean * mean;
  float rstd = rsqrtf(var + 1e-5f);
  unsigned short* yr = y + (size_t)row * DMODEL;
  yr[lane] = f2bf((v0 - mean) * rstd * g[lane] + bb[lane]);
  yr[lane + 64] = f2bf((v1 - mean) * rstd * g[lane + 64] + bb[lane + 64]);
  if (lane < DMODEL - 128)
    yr[lane + 128] = f2bf((v2 - mean) * rstd * g[lane + 128] + bb[lane + 128]);
}

// ------- in_proj MFMA GEMM: A_bf[M,160] @ W_bf[640,160]^T -> xbuf/zbuf fp32 -------
__global__ __launch_bounds__(256)
void k_mm_in(const unsigned short* __restrict__ A, const unsigned short* __restrict__ Wb,
             float* __restrict__ xout, float* __restrict__ zout) {
  __shared__ short As[128 * 40];
  __shared__ short Ws[128 * 40];
  int tid = threadIdx.x;
  int m0 = blockIdx.y * 128, n0 = blockIdx.x * 128;
  int w = tid >> 6, lane = tid & 63;
  int rm = (w >> 1) * 64, cn = (w & 1) * 64;
  int lm = lane & 15, quad = lane >> 4;
  int r = tid >> 1, seg = tid & 1;     // row 0..127, 16-col half
  const unsigned short* pA = A + (size_t)(m0 + r) * DMODEL + seg * 16;
  const unsigned short* pW = Wb + (size_t)(n0 + r) * DMODEL + seg * 16;
  floatx4 acc[4][4];
#pragma unroll
  for (int i = 0; i < 4; ++i)
#pragma unroll
    for (int j = 0; j < 4; ++j)
      acc[i][j] = (floatx4){0.f, 0.f, 0.f, 0.f};
  for (int kt = 0; kt < 5; ++kt) {
    uint4 a0 = *(const uint4*)(pA + kt * 32);
    uint4 a1 = *(const uint4*)(pA + kt * 32 + 8);
    uint4 w0 = *(const uint4*)(pW + kt * 32);
    uint4 w1 = *(const uint4*)(pW + kt * 32 + 8);
    *(short8*)&As[r * 40 + seg * 16]     = *(short8*)&a0;
    *(short8*)&As[r * 40 + seg * 16 + 8] = *(short8*)&a1;
    *(short8*)&Ws[r * 40 + seg * 16]     = *(short8*)&w0;
    *(short8*)&Ws[r * 40 + seg * 16 + 8] = *(short8*)&w1;
    __syncthreads();
    short8 af[4], wf[4];
#pragma unroll
    for (int i = 0; i < 4; ++i)
      af[i] = *(short8*)&As[(rm + i * 16 + lm) * 40 + quad * 8];
#pragma unroll
    for (int j = 0; j < 4; ++j)
      wf[j] = *(short8*)&Ws[(cn + j * 16 + lm) * 40 + quad * 8];
#pragma unroll
    for (int i = 0; i < 4; ++i)
#pragma unroll
      for (int j = 0; j < 4; ++j)
        acc[i][j] = __builtin_amdgcn_mfma_f32_16x16x32_bf16(af[i], wf[j], acc[i][j], 0, 0, 0);
    __syncthreads();
  }
#pragma unroll
  for (int i = 0; i < 4; ++i)
#pragma unroll
    for (int reg = 0; reg < 4; ++reg) {
      int m = m0 + rm + i * 16 + quad * 4 + reg;
#pragma unroll
      for (int j = 0; j < 4; ++j) {
        int n = n0 + cn + j * 16 + lm;
        float v = acc[i][j][reg];
        if (n < DINNER) xout[(size_t)m * DINNER + n] = v;
        else zout[(size_t)m * DINNER + n - DINNER] = v;
      }
    }
}

// ------- generic MFMA GEMM: A_bf[M,K] @ W_bf[N,K]^T (+resid) -> C fp32 [M,N] -------
__global__ __launch_bounds__(256)
void k_mm_g(const unsigned short* __restrict__ A, const unsigned short* __restrict__ Wb,
            float* __restrict__ C, const float* __restrict__ resid, int N, int K) {
  __shared__ short As[128 * 40];
  __shared__ short Ws[64 * 40];
  int tid = threadIdx.x;
  int m0 = blockIdx.y * 128, n0 = blockIdx.x * 64;
  int w = tid >> 6, lane = tid & 63;
  int rm = w * 32;
  int lm = lane & 15, quad = lane >> 4;
  int r = tid >> 1, seg = tid & 1;     // A: row 0..127, 16-col half
  int wr = tid >> 2, wseg = tid & 3;   // W: row 0..63, 8-col quarter
  bool wvld = (n0 + wr) < N;
  const unsigned short* pA = A + (size_t)(m0 + r) * K + seg * 16;
  const unsigned short* pW = Wb + (size_t)(wvld ? (n0 + wr) : 0) * K + wseg * 8;
  floatx4 acc[2][4];
#pragma unroll
  for (int i = 0; i < 2; ++i)
#pragma unroll
    for (int j = 0; j < 4; ++j)
      acc[i][j] = (floatx4){0.f, 0.f, 0.f, 0.f};
  int nk = K >> 5;
  for (int kt = 0; kt < nk; ++kt) {
    uint4 a0 = *(const uint4*)(pA + kt * 32);
    uint4 a1 = *(const uint4*)(pA + kt * 32 + 8);
    uint4 wv = wvld ? *(const uint4*)(pW + kt * 32)
                    : make_uint4(0u, 0u, 0u, 0u);
    *(short8*)&As[r * 40 + seg * 16]     = *(short8*)&a0;
    *(short8*)&As[r * 40 + seg * 16 + 8] = *(short8*)&a1;
    *(short8*)&Ws[wr * 40 + wseg * 8]    = *(short8*)&wv;
    __syncthreads();
    short8 af[2], wf[4];
#pragma unroll
    for (int i = 0; i < 2; ++i)
      af[i] = *(short8*)&As[(rm + i * 16 + lm) * 40 + quad * 8];
#pragma unroll
    for (int j = 0; j < 4; ++j)
      wf[j] = *(short8*)&Ws[(j * 16 + lm) * 40 + quad * 8];
#pragma unroll
    for (int i = 0; i < 2; ++i)
#pragma unroll
      for (int j = 0; j < 4; ++j)
        acc[i][j] = __builtin_amdgcn_mfma_f32_16x16x32_bf16(af[i], wf[j], acc[i][j], 0, 0, 0);
    __syncthreads();
  }
#pragma unroll
  for (int i = 0; i < 2; ++i)
#pragma unroll
    for (int reg = 0; reg < 4; ++reg) {
      int m = m0 + rm + i * 16 + quad * 4 + reg;
#pragma unroll
      for (int j = 0; j < 4; ++j) {
        int n = n0 + j * 16 + lm;
        if (n < N) {
          float v = acc[i][j][reg];
          if (resid) v += resid[(size_t)m * N + n];
          C[(size_t)m * N + n] = v;
        }
      }
    }
}

// ---- depthwise causal conv (k=12) + SiLU: xbuf[tok][d] -> uT[b][d][t] fp32 + u_bf[tok][d] bf16 ----
__global__ __launch_bounds__(256)
void k_convT(const float* __restrict__ xbuf, const float* __restrict__ cw,
             const float* __restrict__ cb, float* __restrict__ uT,
             unsigned short* __restrict__ ubf) {
  int t0 = blockIdx.x * 64, d0 = blockIdx.y * 64, b = blockIdx.z;
  __shared__ float xs[76 * 65];
  __shared__ float us[64 * 65];
  int tid = threadIdx.x, j = tid & 63, w = tid >> 6;
#pragma unroll
  for (int it = 0; it < 19; ++it) {
    int r = it * 4 + w;                 // 0..75
    int t = t0 - (DCONV - 1) + r;
    xs[r * 65 + j] = (t >= 0 && t < TLEN)
        ? xbuf[((size_t)b * TLEN + t) * DINNER + d0 + j] : 0.f;
  }
  __syncthreads();
  float cwr[DCONV];
#pragma unroll
  for (int k = 0; k < DCONV; ++k) cwr[k] = cw[(d0 + j) * DCONV + k];
  float cbv = cb[d0 + j];
#pragma unroll
  for (int it = 0; it < 16; ++it) {
    int tl = it * 4 + w;                // 0..63
    float acc = cbv;
#pragma unroll
    for (int k = 0; k < DCONV; ++k)
      acc = fmaf(cwr[k], xs[(tl + k) * 65 + j], acc);
    us[tl * 65 + j] = acc * sigmoidf_(acc);
  }
  __syncthreads();
#pragma unroll
  for (int it = 0; it < 16; ++it) {
    int tr = it * 4 + w;
    ubf[((size_t)b * TLEN + t0 + tr) * DINNER + d0 + j] = f2bf(us[tr * 65 + j]);
  }
#pragma unroll
  for (int it = 0; it < 16; ++it) {
    int dl = it * 4 + w;
    uT[((size_t)b * DINNER + d0 + dl) * TLEN + t0 + j] = us[j * 65 + dl];
  }
}

// ---- pack: delT = softplus(dt@dtw^T + dtb) time-major fp32; szT = silu(z) time-major bf16 ----
__global__ __launch_bounds__(256)
void k_pack(const float* __restrict__ zbuf, const float* __restrict__ xdbl,
            const float* __restrict__ dtw, const float* __restrict__ dtb,
            float* __restrict__ delT, unsigned short* __restrict__ szT) {
  int t0 = blockIdx.x * 64, d0 = blockIdx.y * 64, b = blockIdx.z;
  __shared__ float zs[64 * 65];
  __shared__ float xd[64 * 13];
  int tid = threadIdx.x, j = tid & 63, w = tid >> 6;
#pragma unroll
  for (int it = 0; it < 16; ++it) {
    int i = it * 4 + w;
    zs[i * 65 + j] = zbuf[((size_t)b * TLEN + t0 + i) * DINNER + d0 + j];
  }
  {
    int r = tid >> 2, c = tid & 3;
    size_t rowb = ((size_t)b * TLEN + t0 + r) * XDBL;
    for (int cc = c; cc < DTRANK; cc += 4)
      xd[r * 13 + cc] = xdbl[rowb + cc];
  }
  __syncthreads();
#pragma unroll
  for (int it = 0; it < 16; ++it) {
    int dl = it * 4 + w, d = d0 + dl;
    float acc = dtb[d];
    const float* wr = dtw + d * DTRANK;
#pragma unroll
    for (int rr = 0; rr < DTRANK; ++rr)
      acc = fmaf(xd[j * 13 + rr], wr[rr], acc);
    float del = (acc > 20.f) ? acc : log1pf(__expf(acc));
    size_t o = ((size_t)b * DINNER + d) * TLEN + t0 + j;
    delT[o] = del;
    float zv = zs[j * 65 + dl];
    szT[o] = f2bf(zv * sigmoidf_(zv));
  }
}

// ---- scan pass A: per (b,d,partition) h-only recurrence from h=0; writes h_local + sum(del) ----
__global__ __launch_bounds__(256)
void k_scan_a(const float* __restrict__ delT, const float* __restrict__ uT,
              const float* __restrict__ xdbl, const float* __restrict__ Alog,
              float* __restrict__ h_loc, float* __restrict__ sumdel) {
  int wave = threadIdx.x >> 6, lane = threadIdx.x & 63;
  int b = blockIdx.x / (DINNER / 4);
  int d = (blockIdx.x % (DINNER / 4)) * 4 + wave;
  int p = blockIdx.y;
  float Al = -__expf(Alog[d * DSTATE + lane]);
  size_t chan = ((size_t)b * DINNER + d) * TLEN;
  const float4* pd4 = (const float4*)(delT + chan + p * PT);
  const float4* pu4 = (const float4*)(uT + chan + p * PT);
  const float* xb = xdbl + ((size_t)b * TLEN + p * PT) * XDBL + DTRANK + lane;
  float h = 0.f, S = 0.f;
  for (int c = 0; c < PT / 4; ++c) {
    float4 d4 = pd4[c], u4 = pu4[c];
    float delv[4] = {d4.x, d4.y, d4.z, d4.w};
    float uv[4] = {u4.x, u4.y, u4.z, u4.w};
#pragma unroll
    for (int t = 0; t < 4; ++t) {
      float Bv = xb[(size_t)(c * 4 + t) * XDBL];
      S += delv[t];
      h = fmaf(h, __expf(delv[t] * Al), delv[t] * uv[t] * Bv);
    }
  }
  size_t slot = ((size_t)b * DINNER + d) * NPART + p;
  h_loc[slot * 64 + lane] = h;
  if (lane == 0) sumdel[slot] = S;
}

// ---- scan combine: sequential prefix over partitions; h_loc[p] <- h_start(p) ----
__global__ __launch_bounds__(256)
void k_scan_c(const float* __restrict__ Alog, const float* __restrict__ sumdel,
              float* __restrict__ h_loc) {
  int wave = threadIdx.x >> 6, lane = threadIdx.x & 63;
  int b = blockIdx.x / (DINNER / 4);
  int d = (blockIdx.x % (DINNER / 4)) * 4 + wave;
  float Al = -__expf(Alog[d * DSTATE + lane]);
  size_t base = ((size_t)b * DINNER + d) * NPART;
  float H = 0.f;
#pragma unroll
  for (int p = 0; p < NPART; ++p) {
    float hl = h_loc[(base + p) * 64 + lane];
    float sd = sumdel[base + p];
    h_loc[(base + p) * 64 + lane] = H;
    H = fmaf(__expf(Al * sd), H, hl);
  }
}

// ---- scan pass B: full y-scan per partition, seeded with h_start; deferred LDS reduce ----
__global__ __launch_bounds__(256)
void k_scan_b(const float* __restrict__ delT, const float* __restrict__ uT,
              const unsigned short* __restrict__ szT, const float* __restrict__ xdbl,
              const float* __restrict__ Alog, const float* __restrict__ Dskip,
              const float* __restrict__ h_loc, float* __restrict__ yT) {
  int wave = threadIdx.x >> 6, lane = threadIdx.x & 63;
  int b = blockIdx.x / (DINNER / 4);
  int d = (blockIdx.x % (DINNER / 4)) * 4 + wave;
  int p = blockIdx.y;
  __shared__ float ps_all[4][16 * 65];
  float* ps = ps_all[wave];               // per-wave region; same-wave DS ops are ordered
  float Al = -__expf(Alog[d * DSTATE + lane]);
  float Dd = Dskip[d];
  size_t chan = ((size_t)b * DINNER + d) * TLEN;
  const float* pd = delT + chan + p * PT;
  const float* pu = uT + chan + p * PT;
  const unsigned short* psz = szT + chan + p * PT;
  float* py = yT + chan + p * PT;
  const float* xb = xdbl + ((size_t)b * TLEN + p * PT) * XDBL + DTRANK + lane;
  float h = h_loc[(((size_t)b * DINNER + d) * NPART + p) * 64 + lane];
  int tl = lane & 15, qq = lane >> 4;
  for (int t0 = 0; t0 < PT; t0 += 16) {
#pragma unroll
    for (int t = 0; t < 16; ++t) {
      float del = pd[t0 + t];
      float uu = pu[t0 + t];
      const float* xr = xb + (size_t)(t0 + t) * XDBL;
      float Bv = xr[0], Cv = xr[DSTATE];
      h = fmaf(h, __expf(del * Al), del * uu * Bv);
      ps[t * 65 + lane] = h * Cv;
    }
    float pp = 0.f;
#pragma unroll
    for (int i = 0; i < 16; ++i)
      pp += ps[tl * 65 + qq * 16 + i];
    pp += __shfl_xor(pp, 16);
    pp += __shfl_xor(pp, 32);
    if (lane < 16) {
      int t = t0 + tl;
      py[t] = (pp + pu[t] * Dd) * bf2f(psz[t]);
    }
  }
}

// ---- transpose yT[b][d][t] fp32 -> y_bf[tok][d] bf16 ----
__global__ __launch_bounds__(256)
void k_t2b(const float* __restrict__ yT, unsigned short* __restrict__ ybf) {
  int t0 = blockIdx.x * 64, d0 = blockIdx.y * 64, b = blockIdx.z;
  __shared__ float ls[64 * 65];
  int tid = threadIdx.x, j = tid & 63, w = tid >> 6;
#pragma unroll
  for (int it = 0; it < 16; ++it) {
    int dl = it * 4 + w;
    ls[dl * 65 + j] = yT[((size_t)b * DINNER + d0 + dl) * TLEN + t0 + j];
  }
  __syncthreads();
#pragma unroll
  for (int it = 0; it < 16; ++it) {
    int tr = it * 4 + w;
    ybf[((size_t)b * TLEN + t0 + tr) * DINNER + d0 + j] = f2bf(ls[j * 65 + tr]);
  }
}

// ---------------- head ----------------
__global__ __launch_bounds__(256)
void k_head(const float* __restrict__ h, const float* __restrict__ hw,
            const float* __restrict__ hb, float* __restrict__ out) {
  int tok = blockIdx.x * 4 + (threadIdx.x >> 6);
  int lane = threadIdx.x & 63;
  const float* hr = h + (size_t)tok * DMODEL;
  float s = hr[lane] * hw[lane] + hr[lane + 64] * hw[lane + 64];
  if (lane < DMODEL - 128) s += hr[lane + 128] * hw[lane + 128];
#pragma unroll
  for (int off = 32; off; off >>= 1) s += __shfl_xor(s, off);
  if (lane == 0) out[tok] = s + hb[0];
}

extern "C" void kernel_launch(void* const* d_in, const int* in_sizes, int n_in,
                              void* d_out, int out_size, void* d_ws, size_t ws_size,
                              hipStream_t stream) {
  const float* x      = (const float*)d_in[0];
  const float* pre_w  = (const float*)d_in[1];
  const float* pre_b  = (const float*)d_in[2];
  const float* ln_g   = (const float*)d_in[3];
  const float* ln_b   = (const float*)d_in[4];
  const float* in_w   = (const float*)d_in[5];
  const float* conv_w = (const float*)d_in[6];
  const float* conv_b = (const float*)d_in[7];
  const float* xproj_w= (const float*)d_in[8];
  const float* dt_w   = (const float*)d_in[9];
  const float* dt_b   = (const float*)d_in[10];
  const float* A_log  = (const float*)d_in[11];
  const float* D_skip = (const float*)d_in[12];
  const float* out_w  = (const float*)d_in[13];
  const float* head_w = (const float*)d_in[14];
  const float* head_b = (const float*)d_in[15];
  float* out = (float*)d_out;

  // workspace (floats), total ~207 MB:
  // h | xdbl | R (lnxd_bf -> u_bf -> delT) |
  // X region (42MB): szT_bf (21MB) + h_loc (10.5MB) + sumdel (0.16MB); y_bf overlaps szT_bf after scan
  // zbuf (-> yT) | uT | wbf
  float* ws   = (float*)d_ws;
  float* h    = ws;
  float* xdbl = h    + (size_t)NTOK * DMODEL;
  float* R    = xdbl + (size_t)NTOK * XDBL;
  float* xbuf = R    + (size_t)NTOK * DINNER;
  float* zbuf = xbuf + (size_t)NTOK * DINNER;
  float* uT   = zbuf + (size_t)NTOK * DINNER;
  unsigned short* wbf = (unsigned short*)(uT + (size_t)NTOK * DINNER);

  unsigned short* lnxd_bf = (unsigned short*)R;
  unsigned short* u_bf    = (unsigned short*)R;
  float*          delT    = R;
  unsigned short* szT_bf  = (unsigned short*)xbuf;
  float*          h_loc   = xbuf + (size_t)NTOK * DINNER / 2;   // after szT_bf (21MB)
  float*          sumdel  = h_loc + (size_t)BATCH * DINNER * NPART * 64;
  unsigned short* y_bf    = (unsigned short*)xbuf;              // after scan (szT dead)
  float*          yT      = zbuf;
  unsigned short* w_in    = wbf;
  unsigned short* w_xp    = wbf + 102400;
  unsigned short* w_ou    = wbf + 146560;

  k_preconv<<<NTOK * DMODEL / 256, 256, 0, stream>>>(x, pre_w, pre_b, h);

  for (int L = 0; L < NBLK; ++L) {
    const float* Al_L = A_log + (size_t)L * DINNER * DSTATE;
    k_cast<<<773, 256, 0, stream>>>(
        in_w + (size_t)L * 640 * DMODEL, xproj_w + (size_t)L * XDBL * DINNER,
        out_w + (size_t)L * DMODEL * DINNER, wbf);
    k_ln<<<NTOK / 4, 256, 0, stream>>>(h, ln_g + L * DMODEL, ln_b + L * DMODEL, lnxd_bf);
    k_mm_in<<<dim3(5, NTOK / 128), 256, 0, stream>>>(lnxd_bf, w_in, xbuf, zbuf);
    k_convT<<<dim3(TLEN / 64, DINNER / 64, BATCH), 256, 0, stream>>>(
        xbuf, conv_w + (size_t)L * DINNER * DCONV, conv_b + (size_t)L * DINNER, uT, u_bf);
    k_mm_g<<<dim3(3, NTOK / 128), 256, 0, stream>>>(u_bf, w_xp, xdbl, nullptr, XDBL, DINNER);
    k_pack<<<dim3(TLEN / 64, DINNER / 64, BATCH), 256, 0, stream>>>(
        zbuf, xdbl, dt_w + (size_t)L * DINNER * DTRANK, dt_b + (size_t)L * DINNER,
        delT, szT_bf);
    k_scan_a<<<dim3(BATCH * (DINNER / 4), NPART), 256, 0, stream>>>(
        delT, uT, xdbl, Al_L, h_loc, sumdel);
    k_scan_c<<<BATCH * (DINNER / 4), 256, 0, stream>>>(Al_L, sumdel, h_loc);
    k_scan_b<<<dim3(BATCH * (DINNER / 4), NPART), 256, 0, stream>>>(
        delT, uT, szT_bf, xdbl, Al_L, D_skip + (size_t)L * DINNER, h_loc, yT);
    k_t2b<<<dim3(TLEN / 64, DINNER / 64, BATCH), 256, 0, stream>>>(yT, y_bf);
    k_mm_g<<<dim3(3, NTOK / 128), 256, 0, stream>>>(y_bf, w_ou, h, h, DMODEL, DINNER);
  }

  k_head<<<NTOK / 4, 256, 0, stream>>>(h, head_w, head_b, out);
}

// Round 8
// 3840.911 us; speedup vs baseline: 1.4640x; 1.4640x over previous
//
#include <hip/hip_runtime.h>
#include <math.h>

#define BATCH 16
#define TLEN 2048
#define NTOK (BATCH*TLEN)       // 32768
#define DMODEL 160
#define DINNER 320
#define DSTATE 64
#define DTRANK 10
#define XDBL 138                // DTRANK + 2*D_STATE
#define DCONV 12
#define PREK 9
#define NBLK 8

typedef __attribute__((ext_vector_type(8))) short short8;
typedef __attribute__((ext_vector_type(4))) float floatx4;

__device__ __forceinline__ float sigmoidf_(float x) { return 1.f / (1.f + __expf(-x)); }
__device__ __forceinline__ unsigned short f2bf(float f) {
  union { float f; unsigned u; } v; v.f = f;
  unsigned r = v.u + 0x7FFF + ((v.u >> 16) & 1);   // round-to-nearest-even
  return (unsigned short)(r >> 16);
}
__device__ __forceinline__ float bf2f(unsigned short s) {
  union { unsigned u; float f; } v; v.u = ((unsigned)s) << 16;
  return v.f;
}

// ---------------- pre conv (k=9, same pad) + exact GELU ----------------
__global__ __launch_bounds__(256)
void k_preconv(const float* __restrict__ x, const float* __restrict__ w,
               const float* __restrict__ bias, float* __restrict__ h) {
  int gid = blockIdx.x * 256 + threadIdx.x;
  if (gid >= NTOK * DMODEL) return;
  int c = gid % DMODEL;
  int tok = gid / DMODEL;
  int b = tok / TLEN, t = tok % TLEN;
  const float* xb = x + (size_t)b * TLEN;
  float acc = bias[c];
#pragma unroll
  for (int k = 0; k < PREK; ++k) {
    int tp = t + k - PREK / 2;
    float xv = (tp >= 0 && tp < TLEN) ? xb[tp] : 0.f;
    acc = fmaf(w[c * PREK + k], xv, acc);
  }
  h[gid] = 0.5f * acc * (1.f + erff(acc * 0.70710678118654752440f));
}

// ---------------- per-layer weight cast to bf16 ----------------
__global__ __launch_bounds__(256)
void k_cast(const float* __restrict__ iw, const float* __restrict__ xw,
            const float* __restrict__ ow, unsigned short* __restrict__ wbf) {
  int i = blockIdx.x * 256 + threadIdx.x;
  if (i < 102400) wbf[i] = f2bf(iw[i]);
  else if (i < 146560) wbf[i] = f2bf(xw[i - 102400]);
  else if (i < 197760) wbf[i] = f2bf(ow[i - 146560]);
}

// ---------------- LayerNorm over d=160 -> bf16 out ----------------
__global__ __launch_bounds__(256)
void k_ln(const float* __restrict__ h, const float* __restrict__ g,
          const float* __restrict__ bb, unsigned short* __restrict__ y) {
  int row = blockIdx.x * 4 + (threadIdx.x >> 6);
  int lane = threadIdx.x & 63;
  const float* hr = h + (size_t)row * DMODEL;
  float v0 = hr[lane], v1 = hr[lane + 64];
  float v2 = (lane < DMODEL - 128) ? hr[lane + 128] : 0.f;
  float s = v0 + v1 + v2;
  float sq = v0 * v0 + v1 * v1 + v2 * v2;
#pragma unroll
  for (int off = 32; off; off >>= 1) {
    s += __shfl_xor(s, off);
    sq += __shfl_xor(sq, off);
  }
  float mean = s * (1.f / DMODEL);
  float var = sq * (1.f / DMODEL) - mean * mean;
  float rstd = rsqrtf(var + 1e-5f);
  unsigned short* yr = y + (size_t)row * DMODEL;
  yr[lane] = f2bf((v0 - mean) * rstd * g[lane] + bb[lane]);
  yr[lane + 64] = f2bf((v1 - mean) * rstd * g[lane + 64] + bb[lane + 64]);
  if (lane < DMODEL - 128)
    yr[lane + 128] = f2bf((v2 - mean) * rstd * g[lane + 128] + bb[lane + 128]);
}

// ------- in_proj MFMA GEMM: A_bf[M,160] @ W_bf[640,160]^T -> x fp32, z bf16 -------
__global__ __launch_bounds__(256)
void k_mm_in(const unsigned short* __restrict__ A, const unsigned short* __restrict__ Wb,
             float* __restrict__ xout, unsigned short* __restrict__ zout) {
  __shared__ short As[128 * 40];
  __shared__ short Ws[128 * 40];
  int tid = threadIdx.x;
  int m0 = blockIdx.y * 128, n0 = blockIdx.x * 128;
  int w = tid >> 6, lane = tid & 63;
  int rm = (w >> 1) * 64, cn = (w & 1) * 64;
  int lm = lane & 15, quad = lane >> 4;
  int r = tid >> 1, seg = tid & 1;     // row 0..127, 16-col half
  const unsigned short* pA = A + (size_t)(m0 + r) * DMODEL + seg * 16;
  const unsigned short* pW = Wb + (size_t)(n0 + r) * DMODEL + seg * 16;
  floatx4 acc[4][4];
#pragma unroll
  for (int i = 0; i < 4; ++i)
#pragma unroll
    for (int j = 0; j < 4; ++j)
      acc[i][j] = (floatx4){0.f, 0.f, 0.f, 0.f};
  for (int kt = 0; kt < 5; ++kt) {
    uint4 a0 = *(const uint4*)(pA + kt * 32);
    uint4 a1 = *(const uint4*)(pA + kt * 32 + 8);
    uint4 w0 = *(const uint4*)(pW + kt * 32);
    uint4 w1 = *(const uint4*)(pW + kt * 32 + 8);
    *(short8*)&As[r * 40 + seg * 16]     = *(short8*)&a0;
    *(short8*)&As[r * 40 + seg * 16 + 8] = *(short8*)&a1;
    *(short8*)&Ws[r * 40 + seg * 16]     = *(short8*)&w0;
    *(short8*)&Ws[r * 40 + seg * 16 + 8] = *(short8*)&w1;
    __syncthreads();
    short8 af[4], wf[4];
#pragma unroll
    for (int i = 0; i < 4; ++i)
      af[i] = *(short8*)&As[(rm + i * 16 + lm) * 40 + quad * 8];
#pragma unroll
    for (int j = 0; j < 4; ++j)
      wf[j] = *(short8*)&Ws[(cn + j * 16 + lm) * 40 + quad * 8];
#pragma unroll
    for (int i = 0; i < 4; ++i)
#pragma unroll
      for (int j = 0; j < 4; ++j)
        acc[i][j] = __builtin_amdgcn_mfma_f32_16x16x32_bf16(af[i], wf[j], acc[i][j], 0, 0, 0);
    __syncthreads();
  }
#pragma unroll
  for (int i = 0; i < 4; ++i)
#pragma unroll
    for (int reg = 0; reg < 4; ++reg) {
      int m = m0 + rm + i * 16 + quad * 4 + reg;
#pragma unroll
      for (int j = 0; j < 4; ++j) {
        int n = n0 + cn + j * 16 + lm;
        float v = acc[i][j][reg];
        if (n < DINNER) xout[(size_t)m * DINNER + n] = v;
        else zout[(size_t)m * DINNER + n - DINNER] = f2bf(v);
      }
    }
}

// ------- out_proj MFMA GEMM: A_bf[M,K] @ W_bf[N,K]^T (+resid) -> C fp32 [M,N] -------
__global__ __launch_bounds__(256)
void k_mm_g(const unsigned short* __restrict__ A, const unsigned short* __restrict__ Wb,
            float* __restrict__ C, const float* __restrict__ resid, int N, int K) {
  __shared__ short As[128 * 40];
  __shared__ short Ws[64 * 40];
  int tid = threadIdx.x;
  int m0 = blockIdx.y * 128, n0 = blockIdx.x * 64;
  int w = tid >> 6, lane = tid & 63;
  int rm = w * 32;
  int lm = lane & 15, quad = lane >> 4;
  int r = tid >> 1, seg = tid & 1;     // A: row 0..127, 16-col half
  int wr = tid >> 2, wseg = tid & 3;   // W: row 0..63, 8-col quarter
  bool wvld = (n0 + wr) < N;
  const unsigned short* pA = A + (size_t)(m0 + r) * K + seg * 16;
  const unsigned short* pW = Wb + (size_t)(wvld ? (n0 + wr) : 0) * K + wseg * 8;
  floatx4 acc[2][4];
#pragma unroll
  for (int i = 0; i < 2; ++i)
#pragma unroll
    for (int j = 0; j < 4; ++j)
      acc[i][j] = (floatx4){0.f, 0.f, 0.f, 0.f};
  int nk = K >> 5;
  for (int kt = 0; kt < nk; ++kt) {
    uint4 a0 = *(const uint4*)(pA + kt * 32);
    uint4 a1 = *(const uint4*)(pA + kt * 32 + 8);
    uint4 wv = wvld ? *(const uint4*)(pW + kt * 32)
                    : make_uint4(0u, 0u, 0u, 0u);
    *(short8*)&As[r * 40 + seg * 16]     = *(short8*)&a0;
    *(short8*)&As[r * 40 + seg * 16 + 8] = *(short8*)&a1;
    *(short8*)&Ws[wr * 40 + wseg * 8]    = *(short8*)&wv;
    __syncthreads();
    short8 af[2], wf[4];
#pragma unroll
    for (int i = 0; i < 2; ++i)
      af[i] = *(short8*)&As[(rm + i * 16 + lm) * 40 + quad * 8];
#pragma unroll
    for (int j = 0; j < 4; ++j)
      wf[j] = *(short8*)&Ws[(j * 16 + lm) * 40 + quad * 8];
#pragma unroll
    for (int i = 0; i < 2; ++i)
#pragma unroll
      for (int j = 0; j < 4; ++j)
        acc[i][j] = __builtin_amdgcn_mfma_f32_16x16x32_bf16(af[i], wf[j], acc[i][j], 0, 0, 0);
    __syncthreads();
  }
#pragma unroll
  for (int i = 0; i < 2; ++i)
#pragma unroll
    for (int reg = 0; reg < 4; ++reg) {
      int m = m0 + rm + i * 16 + quad * 4 + reg;
#pragma unroll
      for (int j = 0; j < 4; ++j) {
        int n = n0 + j * 16 + lm;
        if (n < N) {
          float v = acc[i][j][reg];
          if (resid) v += resid[(size_t)m * N + n];
          C[(size_t)m * N + n] = v;
        }
      }
    }
}

// ------- xproj MFMA GEMM: u_bf[M,320] @ W_bf[138,320]^T -> xdbl bf16 [M,138] -------
__global__ __launch_bounds__(256)
void k_mm_x(const unsigned short* __restrict__ A, const unsigned short* __restrict__ Wb,
            unsigned short* __restrict__ C) {
  const int N = XDBL, K = DINNER;
  __shared__ short As[128 * 40];
  __shared__ short Ws[64 * 40];
  int tid = threadIdx.x;
  int m0 = blockIdx.y * 128, n0 = blockIdx.x * 64;
  int w = tid >> 6, lane = tid & 63;
  int rm = w * 32;
  int lm = lane & 15, quad = lane >> 4;
  int r = tid >> 1, seg = tid & 1;
  int wr = tid >> 2, wseg = tid & 3;
  bool wvld = (n0 + wr) < N;
  const unsigned short* pA = A + (size_t)(m0 + r) * K + seg * 16;
  const unsigned short* pW = Wb + (size_t)(wvld ? (n0 + wr) : 0) * K + wseg * 8;
  floatx4 acc[2][4];
#pragma unroll
  for (int i = 0; i < 2; ++i)
#pragma unroll
    for (int j = 0; j < 4; ++j)
      acc[i][j] = (floatx4){0.f, 0.f, 0.f, 0.f};
  int nk = K >> 5;
  for (int kt = 0; kt < nk; ++kt) {
    uint4 a0 = *(const uint4*)(pA + kt * 32);
    uint4 a1 = *(const uint4*)(pA + kt * 32 + 8);
    uint4 wv = wvld ? *(const uint4*)(pW + kt * 32)
                    : make_uint4(0u, 0u, 0u, 0u);
    *(short8*)&As[r * 40 + seg * 16]     = *(short8*)&a0;
    *(short8*)&As[r * 40 + seg * 16 + 8] = *(short8*)&a1;
    *(short8*)&Ws[wr * 40 + wseg * 8]    = *(short8*)&wv;
    __syncthreads();
    short8 af[2], wf[4];
#pragma unroll
    for (int i = 0; i < 2; ++i)
      af[i] = *(short8*)&As[(rm + i * 16 + lm) * 40 + quad * 8];
#pragma unroll
    for (int j = 0; j < 4; ++j)
      wf[j] = *(short8*)&Ws[(j * 16 + lm) * 40 + quad * 8];
#pragma unroll
    for (int i = 0; i < 2; ++i)
#pragma unroll
      for (int j = 0; j < 4; ++j)
        acc[i][j] = __builtin_amdgcn_mfma_f32_16x16x32_bf16(af[i], wf[j], acc[i][j], 0, 0, 0);
    __syncthreads();
  }
#pragma unroll
  for (int i = 0; i < 2; ++i)
#pragma unroll
    for (int reg = 0; reg < 4; ++reg) {
      int m = m0 + rm + i * 16 + quad * 4 + reg;
#pragma unroll
      for (int j = 0; j < 4; ++j) {
        int n = n0 + j * 16 + lm;
        if (n < N) C[(size_t)m * N + n] = f2bf(acc[i][j][reg]);
      }
    }
}

// ---- depthwise causal conv (k=12) + SiLU: xbuf[tok][d] -> u_bf token-major + uT_bf time-major ----
__global__ __launch_bounds__(256)
void k_convT(const float* __restrict__ xbuf, const float* __restrict__ cw,
             const float* __restrict__ cb, unsigned short* __restrict__ uTb,
             unsigned short* __restrict__ ubf) {
  int t0 = blockIdx.x * 64, d0 = blockIdx.y * 64, b = blockIdx.z;
  __shared__ float xs[76 * 65];
  __shared__ float us[64 * 65];
  int tid = threadIdx.x, j = tid & 63, w = tid >> 6;
#pragma unroll
  for (int it = 0; it < 19; ++it) {
    int r = it * 4 + w;                 // 0..75
    int t = t0 - (DCONV - 1) + r;
    xs[r * 65 + j] = (t >= 0 && t < TLEN)
        ? xbuf[((size_t)b * TLEN + t) * DINNER + d0 + j] : 0.f;
  }
  __syncthreads();
  float cwr[DCONV];
#pragma unroll
  for (int k = 0; k < DCONV; ++k) cwr[k] = cw[(d0 + j) * DCONV + k];
  float cbv = cb[d0 + j];
#pragma unroll
  for (int it = 0; it < 16; ++it) {
    int tl = it * 4 + w;                // 0..63
    float acc = cbv;
#pragma unroll
    for (int k = 0; k < DCONV; ++k)
      acc = fmaf(cwr[k], xs[(tl + k) * 65 + j], acc);
    us[tl * 65 + j] = acc * sigmoidf_(acc);
  }
  __syncthreads();
#pragma unroll
  for (int it = 0; it < 16; ++it) {
    int tr = it * 4 + w;
    ubf[((size_t)b * TLEN + t0 + tr) * DINNER + d0 + j] = f2bf(us[tr * 65 + j]);
  }
#pragma unroll
  for (int it = 0; it < 16; ++it) {
    int dl = it * 4 + w;
    uTb[((size_t)b * DINNER + d0 + dl) * TLEN + t0 + j] = f2bf(us[j * 65 + dl]);
  }
}

// ---- pack: delT = softplus(dt@dtw^T + dtb) time-major fp32; szT = silu(z) time-major bf16 ----
__global__ __launch_bounds__(256)
void k_pack(const unsigned short* __restrict__ zbuf, const unsigned short* __restrict__ xdbl,
            const float* __restrict__ dtw, const float* __restrict__ dtb,
            float* __restrict__ delT, unsigned short* __restrict__ szT) {
  int t0 = blockIdx.x * 64, d0 = blockIdx.y * 64, b = blockIdx.z;
  __shared__ float zs[64 * 65];
  __shared__ float xd[64 * 13];
  int tid = threadIdx.x, j = tid & 63, w = tid >> 6;
#pragma unroll
  for (int it = 0; it < 16; ++it) {
    int i = it * 4 + w;
    zs[i * 65 + j] = bf2f(zbuf[((size_t)b * TLEN + t0 + i) * DINNER + d0 + j]);
  }
  {
    int r = tid >> 2, c = tid & 3;
    size_t rowb = ((size_t)b * TLEN + t0 + r) * XDBL;
    for (int cc = c; cc < DTRANK; cc += 4)
      xd[r * 13 + cc] = bf2f(xdbl[rowb + cc]);
  }
  __syncthreads();
#pragma unroll
  for (int it = 0; it < 16; ++it) {
    int dl = it * 4 + w, d = d0 + dl;
    float acc = dtb[d];
    const float* wr = dtw + d * DTRANK;
#pragma unroll
    for (int rr = 0; rr < DTRANK; ++rr)
      acc = fmaf(xd[j * 13 + rr], wr[rr], acc);
    float del = (acc > 20.f) ? acc : log1pf(__expf(acc));
    size_t o = ((size_t)b * DINNER + d) * TLEN + t0 + j;
    delT[o] = del;
    float zv = zs[j * 65 + dl];
    szT[o] = f2bf(zv * sigmoidf_(zv));
  }
}

// ---------------- selective scan: wave per (b,d), lane = state; no barriers ----------------
// Loads: del fp32 broadcast, u bf16 broadcast, B/C bf16 coalesced. y out bf16 time-major.
// Deferred per-16t LDS reduce with ds_read_b128 (row stride 68 for 16B alignment).
__global__ __launch_bounds__(256)
void k_scan(const float* __restrict__ delT, const unsigned short* __restrict__ uTb,
            const unsigned short* __restrict__ szT, const unsigned short* __restrict__ xdbl,
            const float* __restrict__ Alog, const float* __restrict__ Dskip,
            unsigned short* __restrict__ yTb) {
  int wave = threadIdx.x >> 6, lane = threadIdx.x & 63;
  int b = blockIdx.x / (DINNER / 4);
  int d = (blockIdx.x % (DINNER / 4)) * 4 + wave;
  __shared__ float ps_all[4][16 * 68];
  float* ps = ps_all[wave];               // per-wave region; same-wave DS ops are ordered
  float Al2 = -__expf(Alog[d * DSTATE + lane]) * 1.44269504088896340736f; // pre-scaled for exp2
  float Dd = Dskip[d];
  size_t chan = ((size_t)b * DINNER + d) * TLEN;
  const float* pd = delT + chan;
  const unsigned short* pu = uTb + chan;
  const unsigned short* psz = szT + chan;
  unsigned short* py = yTb + chan;
  const unsigned short* xb = xdbl + (size_t)b * TLEN * XDBL + DTRANK + lane;
  float h = 0.f;
  int tl = lane & 15, qq = lane >> 4;
  for (int t0 = 0; t0 < TLEN; t0 += 16) {
#pragma unroll
    for (int t = 0; t < 16; ++t) {
      float del = pd[t0 + t];
      float uu = bf2f(pu[t0 + t]);
      const unsigned short* xr = xb + (size_t)(t0 + t) * XDBL;
      float Bv = bf2f(xr[0]), Cv = bf2f(xr[DSTATE]);
      h = fmaf(h, exp2f(del * Al2), del * uu * Bv);
      ps[t * 68 + lane] = h * Cv;
    }
    float p = 0.f;
    const floatx4* pr = (const floatx4*)&ps[tl * 68 + qq * 16];
#pragma unroll
    for (int i = 0; i < 4; ++i) {
      floatx4 v = pr[i];
      p += v[0] + v[1] + v[2] + v[3];
    }
    p += __shfl_xor(p, 16);
    p += __shfl_xor(p, 32);
    if (lane < 16) {
      int t = t0 + tl;
      float uu = bf2f(pu[t]);
      py[t] = f2bf((p + uu * Dd) * bf2f(psz[t]));
    }
  }
}

// ---- transpose yT_bf[b][d][t] -> y_bf[tok][d] (bf16 -> bf16) ----
__global__ __launch_bounds__(256)
void k_t2b(const unsigned short* __restrict__ yTb, unsigned short* __restrict__ ybf) {
  int t0 = blockIdx.x * 64, d0 = blockIdx.y * 64, b = blockIdx.z;
  __shared__ unsigned short ls[64 * 66];
  int tid = threadIdx.x, j = tid & 63, w = tid >> 6;
#pragma unroll
  for (int it = 0; it < 16; ++it) {
    int dl = it * 4 + w;
    ls[dl * 66 + j] = yTb[((size_t)b * DINNER + d0 + dl) * TLEN + t0 + j];
  }
  __syncthreads();
#pragma unroll
  for (int it = 0; it < 16; ++it) {
    int tr = it * 4 + w;
    ybf[((size_t)b * TLEN + t0 + tr) * DINNER + d0 + j] = ls[j * 66 + tr];
  }
}

// ---------------- head ----------------
__global__ __launch_bounds__(256)
void k_head(const float* __restrict__ h, const float* __restrict__ hw,
            const float* __restrict__ hb, float* __restrict__ out) {
  int tok = blockIdx.x * 4 + (threadIdx.x >> 6);
  int lane = threadIdx.x & 63;
  const float* hr = h + (size_t)tok * DMODEL;
  float s = hr[lane] * hw[lane] + hr[lane + 64] * hw[lane + 64];
  if (lane < DMODEL - 128) s += hr[lane + 128] * hw[lane + 128];
#pragma unroll
  for (int off = 32; off; off >>= 1) s += __shfl_xor(s, off);
  if (lane == 0) out[tok] = s + hb[0];
}

extern "C" void kernel_launch(void* const* d_in, const int* in_sizes, int n_in,
                              void* d_out, int out_size, void* d_ws, size_t ws_size,
                              hipStream_t stream) {
  const float* x      = (const float*)d_in[0];
  const float* pre_w  = (const float*)d_in[1];
  const float* pre_b  = (const float*)d_in[2];
  const float* ln_g   = (const float*)d_in[3];
  const float* ln_b   = (const float*)d_in[4];
  const float* in_w   = (const float*)d_in[5];
  const float* conv_w = (const float*)d_in[6];
  const float* conv_b = (const float*)d_in[7];
  const float* xproj_w= (const float*)d_in[8];
  const float* dt_w   = (const float*)d_in[9];
  const float* dt_b   = (const float*)d_in[10];
  const float* A_log  = (const float*)d_in[11];
  const float* D_skip = (const float*)d_in[12];
  const float* out_w  = (const float*)d_in[13];
  const float* head_w = (const float*)d_in[14];
  const float* head_b = (const float*)d_in[15];
  float* out = (float*)d_out;

  // workspace (float units), total 44.30M f = 177.2 MB:
  // h | xdbl_bf | delT | uT_bf | X(xbuf -> szT -> y_bf) | Y(zbuf_bf -> yT_bf) |
  // Z(lnxd_bf -> u_bf) | wbf
  float* ws = (float*)d_ws;
  float* h    = ws;
  unsigned short* xdbl_bf = (unsigned short*)(h + (size_t)NTOK * DMODEL);
  float* delT = (float*)(xdbl_bf + (size_t)NTOK * XDBL);
  // pad xdbl_bf region to even float count (NTOK*XDBL even -> ok)
  unsigned short* uT_bf = (unsigned short*)(delT + (size_t)NTOK * DINNER);
  float* X    = (float*)(uT_bf + (size_t)NTOK * DINNER);
  float* Y    = X + (size_t)NTOK * DINNER;                 // 42 MB region X
  float* Z    = Y + (size_t)NTOK * DINNER / 2;             // 21 MB region Y
  unsigned short* wbf = (unsigned short*)(Z + (size_t)NTOK * DINNER / 2); // after 21 MB Z

  float*          xbuf    = X;
  unsigned short* szT     = (unsigned short*)X;
  unsigned short* y_bf    = (unsigned short*)X;   // after scan (szT dead at t2b time)
  unsigned short* zbuf_bf = (unsigned short*)Y;
  unsigned short* yT_bf   = (unsigned short*)Y;   // after pack (zbuf dead)
  unsigned short* lnxd_bf = (unsigned short*)Z;
  unsigned short* u_bf    = (unsigned short*)Z;   // after mm_in (lnxd dead)
  unsigned short* w_in    = wbf;
  unsigned short* w_xp    = wbf + 102400;
  unsigned short* w_ou    = wbf + 146560;

  k_preconv<<<NTOK * DMODEL / 256, 256, 0, stream>>>(x, pre_w, pre_b, h);

  for (int L = 0; L < NBLK; ++L) {
    k_cast<<<773, 256, 0, stream>>>(
        in_w + (size_t)L * 640 * DMODEL, xproj_w + (size_t)L * XDBL * DINNER,
        out_w + (size_t)L * DMODEL * DINNER, wbf);
    k_ln<<<NTOK / 4, 256, 0, stream>>>(h, ln_g + L * DMODEL, ln_b + L * DMODEL, lnxd_bf);
    k_mm_in<<<dim3(5, NTOK / 128), 256, 0, stream>>>(lnxd_bf, w_in, xbuf, zbuf_bf);
    k_convT<<<dim3(TLEN / 64, DINNER / 64, BATCH), 256, 0, stream>>>(
        xbuf, conv_w + (size_t)L * DINNER * DCONV, conv_b + (size_t)L * DINNER,
        uT_bf, u_bf);
    k_mm_x<<<dim3(3, NTOK / 128), 256, 0, stream>>>(u_bf, w_xp, xdbl_bf);
    k_pack<<<dim3(TLEN / 64, DINNER / 64, BATCH), 256, 0, stream>>>(
        zbuf_bf, xdbl_bf, dt_w + (size_t)L * DINNER * DTRANK, dt_b + (size_t)L * DINNER,
        delT, szT);
    k_scan<<<BATCH * (DINNER / 4), 256, 0, stream>>>(
        delT, uT_bf, szT, xdbl_bf, A_log + (size_t)L * DINNER * DSTATE,
        D_skip + (size_t)L * DINNER, yT_bf);
    k_t2b<<<dim3(TLEN / 64, DINNER / 64, BATCH), 256, 0, stream>>>(yT_bf, y_bf);
    k_mm_g<<<dim3(3, NTOK / 128), 256, 0, stream>>>(y_bf, w_ou, h, h, DMODEL, DINNER);
  }

  k_head<<<NTOK / 4, 256, 0, stream>>>(h, head_w, head_b, out);
}

// Round 9
// 3640.440 us; speedup vs baseline: 1.5446x; 1.0551x over previous
//
#include <hip/hip_runtime.h>
#include <math.h>

#define BATCH 16
#define TLEN 2048
#define NTOK (BATCH*TLEN)       // 32768
#define DMODEL 160
#define DINNER 320
#define DSTATE 64
#define DTRANK 10
#define XDBL 138                // DT_RANK + 2*D_STATE (logical)
#define XP 140                  // padded interleaved row: 10 dt + 2 pad + 64 (B,C) pairs
#define DCONV 12
#define PREK 9
#define NBLK 8

typedef __attribute__((ext_vector_type(8))) short short8;
typedef __attribute__((ext_vector_type(4))) float floatx4;

__device__ __forceinline__ float sigmoidf_(float x) { return 1.f / (1.f + __expf(-x)); }
__device__ __forceinline__ unsigned short f2bf(float f) {
  union { float f; unsigned u; } v; v.f = f;
  unsigned r = v.u + 0x7FFF + ((v.u >> 16) & 1);   // round-to-nearest-even
  return (unsigned short)(r >> 16);
}
__device__ __forceinline__ float bf2f(unsigned short s) {
  union { unsigned u; float f; } v; v.u = ((unsigned)s) << 16;
  return v.f;
}
__device__ __forceinline__ float bflo(unsigned u) {   // low short -> float
  union { unsigned u; float f; } v; v.u = u << 16; return v.f;
}
__device__ __forceinline__ float bfhi(unsigned u) {   // high short -> float
  union { unsigned u; float f; } v; v.u = u & 0xFFFF0000u; return v.f;
}

// ---------------- pre conv (k=9, same pad) + exact GELU ----------------
__global__ __launch_bounds__(256)
void k_preconv(const float* __restrict__ x, const float* __restrict__ w,
               const float* __restrict__ bias, float* __restrict__ h) {
  int gid = blockIdx.x * 256 + threadIdx.x;
  if (gid >= NTOK * DMODEL) return;
  int c = gid % DMODEL;
  int tok = gid / DMODEL;
  int b = tok / TLEN, t = tok % TLEN;
  const float* xb = x + (size_t)b * TLEN;
  float acc = bias[c];
#pragma unroll
  for (int k = 0; k < PREK; ++k) {
    int tp = t + k - PREK / 2;
    float xv = (tp >= 0 && tp < TLEN) ? xb[tp] : 0.f;
    acc = fmaf(w[c * PREK + k], xv, acc);
  }
  h[gid] = 0.5f * acc * (1.f + erff(acc * 0.70710678118654752440f));
}

// ---------------- per-layer weight cast to bf16 ----------------
__global__ __launch_bounds__(256)
void k_cast(const float* __restrict__ iw, const float* __restrict__ xw,
            const float* __restrict__ ow, unsigned short* __restrict__ wbf) {
  int i = blockIdx.x * 256 + threadIdx.x;
  if (i < 102400) wbf[i] = f2bf(iw[i]);
  else if (i < 146560) wbf[i] = f2bf(xw[i - 102400]);
  else if (i < 197760) wbf[i] = f2bf(ow[i - 146560]);
}

// ---------------- LayerNorm over d=160 -> bf16 out ----------------
__global__ __launch_bounds__(256)
void k_ln(const float* __restrict__ h, const float* __restrict__ g,
          const float* __restrict__ bb, unsigned short* __restrict__ y) {
  int row = blockIdx.x * 4 + (threadIdx.x >> 6);
  int lane = threadIdx.x & 63;
  const float* hr = h + (size_t)row * DMODEL;
  float v0 = hr[lane], v1 = hr[lane + 64];
  float v2 = (lane < DMODEL - 128) ? hr[lane + 128] : 0.f;
  float s = v0 + v1 + v2;
  float sq = v0 * v0 + v1 * v1 + v2 * v2;
#pragma unroll
  for (int off = 32; off; off >>= 1) {
    s += __shfl_xor(s, off);
    sq += __shfl_xor(sq, off);
  }
  float mean = s * (1.f / DMODEL);
  float var = sq * (1.f / DMODEL) - mean * mean;
  float rstd = rsqrtf(var + 1e-5f);
  unsigned short* yr = y + (size_t)row * DMODEL;
  yr[lane] = f2bf((v0 - mean) * rstd * g[lane] + bb[lane]);
  yr[lane + 64] = f2bf((v1 - mean) * rstd * g[lane + 64] + bb[lane + 64]);
  if (lane < DMODEL - 128)
    yr[lane + 128] = f2bf((v2 - mean) * rstd * g[lane + 128] + bb[lane + 128]);
}

// ------- in_proj MFMA GEMM: A_bf[M,160] @ W_bf[640,160]^T -> x fp32, z bf16 -------
__global__ __launch_bounds__(256)
void k_mm_in(const unsigned short* __restrict__ A, const unsigned short* __restrict__ Wb,
             float* __restrict__ xout, unsigned short* __restrict__ zout) {
  __shared__ short As[128 * 40];
  __shared__ short Ws[128 * 40];
  int tid = threadIdx.x;
  int m0 = blockIdx.y * 128, n0 = blockIdx.x * 128;
  int w = tid >> 6, lane = tid & 63;
  int rm = (w >> 1) * 64, cn = (w & 1) * 64;
  int lm = lane & 15, quad = lane >> 4;
  int r = tid >> 1, seg = tid & 1;
  const unsigned short* pA = A + (size_t)(m0 + r) * DMODEL + seg * 16;
  const unsigned short* pW = Wb + (size_t)(n0 + r) * DMODEL + seg * 16;
  floatx4 acc[4][4];
#pragma unroll
  for (int i = 0; i < 4; ++i)
#pragma unroll
    for (int j = 0; j < 4; ++j)
      acc[i][j] = (floatx4){0.f, 0.f, 0.f, 0.f};
  for (int kt = 0; kt < 5; ++kt) {
    uint4 a0 = *(const uint4*)(pA + kt * 32);
    uint4 a1 = *(const uint4*)(pA + kt * 32 + 8);
    uint4 w0 = *(const uint4*)(pW + kt * 32);
    uint4 w1 = *(const uint4*)(pW + kt * 32 + 8);
    *(short8*)&As[r * 40 + seg * 16]     = *(short8*)&a0;
    *(short8*)&As[r * 40 + seg * 16 + 8] = *(short8*)&a1;
    *(short8*)&Ws[r * 40 + seg * 16]     = *(short8*)&w0;
    *(short8*)&Ws[r * 40 + seg * 16 + 8] = *(short8*)&w1;
    __syncthreads();
    short8 af[4], wf[4];
#pragma unroll
    for (int i = 0; i < 4; ++i)
      af[i] = *(short8*)&As[(rm + i * 16 + lm) * 40 + quad * 8];
#pragma unroll
    for (int j = 0; j < 4; ++j)
      wf[j] = *(short8*)&Ws[(cn + j * 16 + lm) * 40 + quad * 8];
#pragma unroll
    for (int i = 0; i < 4; ++i)
#pragma unroll
      for (int j = 0; j < 4; ++j)
        acc[i][j] = __builtin_amdgcn_mfma_f32_16x16x32_bf16(af[i], wf[j], acc[i][j], 0, 0, 0);
    __syncthreads();
  }
#pragma unroll
  for (int i = 0; i < 4; ++i)
#pragma unroll
    for (int reg = 0; reg < 4; ++reg) {
      int m = m0 + rm + i * 16 + quad * 4 + reg;
#pragma unroll
      for (int j = 0; j < 4; ++j) {
        int n = n0 + cn + j * 16 + lm;
        float v = acc[i][j][reg];
        if (n < DINNER) xout[(size_t)m * DINNER + n] = v;
        else zout[(size_t)m * DINNER + n - DINNER] = f2bf(v);
      }
    }
}

// ------- out_proj MFMA GEMM: A_bf[M,K] @ W_bf[N,K]^T (+resid) -> C fp32 [M,N] -------
__global__ __launch_bounds__(256)
void k_mm_g(const unsigned short* __restrict__ A, const unsigned short* __restrict__ Wb,
            float* __restrict__ C, const float* __restrict__ resid, int N, int K) {
  __shared__ short As[128 * 40];
  __shared__ short Ws[64 * 40];
  int tid = threadIdx.x;
  int m0 = blockIdx.y * 128, n0 = blockIdx.x * 64;
  int w = tid >> 6, lane = tid & 63;
  int rm = w * 32;
  int lm = lane & 15, quad = lane >> 4;
  int r = tid >> 1, seg = tid & 1;
  int wr = tid >> 2, wseg = tid & 3;
  bool wvld = (n0 + wr) < N;
  const unsigned short* pA = A + (size_t)(m0 + r) * K + seg * 16;
  const unsigned short* pW = Wb + (size_t)(wvld ? (n0 + wr) : 0) * K + wseg * 8;
  floatx4 acc[2][4];
#pragma unroll
  for (int i = 0; i < 2; ++i)
#pragma unroll
    for (int j = 0; j < 4; ++j)
      acc[i][j] = (floatx4){0.f, 0.f, 0.f, 0.f};
  int nk = K >> 5;
  for (int kt = 0; kt < nk; ++kt) {
    uint4 a0 = *(const uint4*)(pA + kt * 32);
    uint4 a1 = *(const uint4*)(pA + kt * 32 + 8);
    uint4 wv = wvld ? *(const uint4*)(pW + kt * 32)
                    : make_uint4(0u, 0u, 0u, 0u);
    *(short8*)&As[r * 40 + seg * 16]     = *(short8*)&a0;
    *(short8*)&As[r * 40 + seg * 16 + 8] = *(short8*)&a1;
    *(short8*)&Ws[wr * 40 + wseg * 8]    = *(short8*)&wv;
    __syncthreads();
    short8 af[2], wf[4];
#pragma unroll
    for (int i = 0; i < 2; ++i)
      af[i] = *(short8*)&As[(rm + i * 16 + lm) * 40 + quad * 8];
#pragma unroll
    for (int j = 0; j < 4; ++j)
      wf[j] = *(short8*)&Ws[(j * 16 + lm) * 40 + quad * 8];
#pragma unroll
    for (int i = 0; i < 2; ++i)
#pragma unroll
      for (int j = 0; j < 4; ++j)
        acc[i][j] = __builtin_amdgcn_mfma_f32_16x16x32_bf16(af[i], wf[j], acc[i][j], 0, 0, 0);
    __syncthreads();
  }
#pragma unroll
  for (int i = 0; i < 2; ++i)
#pragma unroll
    for (int reg = 0; reg < 4; ++reg) {
      int m = m0 + rm + i * 16 + quad * 4 + reg;
#pragma unroll
      for (int j = 0; j < 4; ++j) {
        int n = n0 + j * 16 + lm;
        if (n < N) {
          float v = acc[i][j][reg];
          if (resid) v += resid[(size_t)m * N + n];
          C[(size_t)m * N + n] = v;
        }
      }
    }
}

// ------- xproj MFMA GEMM -> interleaved bf16 rows [M][XP]: dt(10)+pad(2)+ (B_s,C_s) pairs -------
__global__ __launch_bounds__(256)
void k_mm_x(const unsigned short* __restrict__ A, const unsigned short* __restrict__ Wb,
            unsigned short* __restrict__ C) {
  const int N = XDBL, K = DINNER;
  __shared__ short As[128 * 40];
  __shared__ short Ws[64 * 40];
  int tid = threadIdx.x;
  int m0 = blockIdx.y * 128, n0 = blockIdx.x * 64;
  int w = tid >> 6, lane = tid & 63;
  int rm = w * 32;
  int lm = lane & 15, quad = lane >> 4;
  int r = tid >> 1, seg = tid & 1;
  int wr = tid >> 2, wseg = tid & 3;
  bool wvld = (n0 + wr) < N;
  const unsigned short* pA = A + (size_t)(m0 + r) * K + seg * 16;
  const unsigned short* pW = Wb + (size_t)(wvld ? (n0 + wr) : 0) * K + wseg * 8;
  floatx4 acc[2][4];
#pragma unroll
  for (int i = 0; i < 2; ++i)
#pragma unroll
    for (int j = 0; j < 4; ++j)
      acc[i][j] = (floatx4){0.f, 0.f, 0.f, 0.f};
  int nk = K >> 5;
  for (int kt = 0; kt < nk; ++kt) {
    uint4 a0 = *(const uint4*)(pA + kt * 32);
    uint4 a1 = *(const uint4*)(pA + kt * 32 + 8);
    uint4 wv = wvld ? *(const uint4*)(pW + kt * 32)
                    : make_uint4(0u, 0u, 0u, 0u);
    *(short8*)&As[r * 40 + seg * 16]     = *(short8*)&a0;
    *(short8*)&As[r * 40 + seg * 16 + 8] = *(short8*)&a1;
    *(short8*)&Ws[wr * 40 + wseg * 8]    = *(short8*)&wv;
    __syncthreads();
    short8 af[2], wf[4];
#pragma unroll
    for (int i = 0; i < 2; ++i)
      af[i] = *(short8*)&As[(rm + i * 16 + lm) * 40 + quad * 8];
#pragma unroll
    for (int j = 0; j < 4; ++j)
      wf[j] = *(short8*)&Ws[(j * 16 + lm) * 40 + quad * 8];
#pragma unroll
    for (int i = 0; i < 2; ++i)
#pragma unroll
      for (int j = 0; j < 4; ++j)
        acc[i][j] = __builtin_amdgcn_mfma_f32_16x16x32_bf16(af[i], wf[j], acc[i][j], 0, 0, 0);
    __syncthreads();
  }
#pragma unroll
  for (int i = 0; i < 2; ++i)
#pragma unroll
    for (int reg = 0; reg < 4; ++reg) {
      int m = m0 + rm + i * 16 + quad * 4 + reg;
#pragma unroll
      for (int j = 0; j < 4; ++j) {
        int n = n0 + j * 16 + lm;
        if (n < N) {
          int slot = (n < DTRANK) ? n
                   : (n < DTRANK + DSTATE) ? 12 + 2 * (n - DTRANK)
                                           : 13 + 2 * (n - DTRANK - DSTATE);
          C[(size_t)m * XP + slot] = f2bf(acc[i][j][reg]);
        }
      }
    }
}

// ---- depthwise causal conv (k=12) + SiLU: xbuf[tok][d] -> u_bf token-major + uT_bf time-major ----
__global__ __launch_bounds__(256)
void k_convT(const float* __restrict__ xbuf, const float* __restrict__ cw,
             const float* __restrict__ cb, unsigned short* __restrict__ uTb,
             unsigned short* __restrict__ ubf) {
  int t0 = blockIdx.x * 64, d0 = blockIdx.y * 64, b = blockIdx.z;
  __shared__ float xs[76 * 65];
  __shared__ float us[64 * 65];
  int tid = threadIdx.x, j = tid & 63, w = tid >> 6;
#pragma unroll
  for (int it = 0; it < 19; ++it) {
    int r = it * 4 + w;                 // 0..75
    int t = t0 - (DCONV - 1) + r;
    xs[r * 65 + j] = (t >= 0 && t < TLEN)
        ? xbuf[((size_t)b * TLEN + t) * DINNER + d0 + j] : 0.f;
  }
  __syncthreads();
  float cwr[DCONV];
#pragma unroll
  for (int k = 0; k < DCONV; ++k) cwr[k] = cw[(d0 + j) * DCONV + k];
  float cbv = cb[d0 + j];
#pragma unroll
  for (int it = 0; it < 16; ++it) {
    int tl = it * 4 + w;                // 0..63
    float acc = cbv;
#pragma unroll
    for (int k = 0; k < DCONV; ++k)
      acc = fmaf(cwr[k], xs[(tl + k) * 65 + j], acc);
    us[tl * 65 + j] = acc * sigmoidf_(acc);
  }
  __syncthreads();
#pragma unroll
  for (int it = 0; it < 16; ++it) {
    int tr = it * 4 + w;
    ubf[((size_t)b * TLEN + t0 + tr) * DINNER + d0 + j] = f2bf(us[tr * 65 + j]);
  }
#pragma unroll
  for (int it = 0; it < 16; ++it) {
    int dl = it * 4 + w;
    uTb[((size_t)b * DINNER + d0 + dl) * TLEN + t0 + j] = f2bf(us[j * 65 + dl]);
  }
}

// ---- pack v2: qT = {del, del*u} float2 time-major; eT = {skip=u*D*ssz | ssz<<16} uint ----
__global__ __launch_bounds__(256)
void k_pack(const unsigned short* __restrict__ zbuf, const unsigned short* __restrict__ xdbl,
            const unsigned short* __restrict__ uTb,
            const float* __restrict__ dtw, const float* __restrict__ dtb,
            const float* __restrict__ Dskip,
            float2* __restrict__ qT, unsigned* __restrict__ eT) {
  int t0 = blockIdx.x * 64, d0 = blockIdx.y * 64, b = blockIdx.z;
  __shared__ float zs[64 * 65];
  __shared__ float xd[64 * 13];
  int tid = threadIdx.x, j = tid & 63, w = tid >> 6;
#pragma unroll
  for (int it = 0; it < 16; ++it) {
    int i = it * 4 + w;
    zs[i * 65 + j] = bf2f(zbuf[((size_t)b * TLEN + t0 + i) * DINNER + d0 + j]);
  }
  {
    int r = tid >> 2, c = tid & 3;
    size_t rowb = ((size_t)b * TLEN + t0 + r) * XP;
    for (int cc = c; cc < DTRANK; cc += 4)
      xd[r * 13 + cc] = bf2f(xdbl[rowb + cc]);
  }
  __syncthreads();
#pragma unroll
  for (int it = 0; it < 16; ++it) {
    int dl = it * 4 + w, d = d0 + dl;
    float acc = dtb[d];
    const float* wr = dtw + d * DTRANK;
#pragma unroll
    for (int rr = 0; rr < DTRANK; ++rr)
      acc = fmaf(xd[j * 13 + rr], wr[rr], acc);
    float del = (acc > 20.f) ? acc : log1pf(__expf(acc));
    size_t o = ((size_t)b * DINNER + d) * TLEN + t0 + j;
    float uv = bf2f(uTb[o]);
    float zv = zs[j * 65 + dl];
    float ssz = zv * sigmoidf_(zv);
    qT[o] = make_float2(del, del * uv);
    unsigned lo = f2bf(uv * Dskip[d] * ssz);
    unsigned hi = f2bf(ssz);
    eT[o] = lo | (hi << 16);
  }
}

// ---------------- selective scan: wave per (b,d), lane = state; no barriers ----------------
// Per t: one b64 (del,delu) broadcast + one b32 (B,C pair) coalesced; 7 VALU + exp2.
__global__ __launch_bounds__(256)
void k_scan(const float2* __restrict__ qT, const unsigned* __restrict__ eT,
            const unsigned short* __restrict__ xdbl, const float* __restrict__ Alog,
            unsigned short* __restrict__ yTb) {
  int wave = threadIdx.x >> 6, lane = threadIdx.x & 63;
  int b = blockIdx.x / (DINNER / 4);
  int d = (blockIdx.x % (DINNER / 4)) * 4 + wave;
  __shared__ float ps_all[4][16 * 68];
  float* ps = ps_all[wave];               // per-wave region; same-wave DS ops are ordered
  float Al2 = -__expf(Alog[d * DSTATE + lane]) * 1.44269504088896340736f;
  size_t chan = ((size_t)b * DINNER + d) * TLEN;
  const float2* pq = qT + chan;
  const unsigned* pe = eT + chan;
  unsigned short* py = yTb + chan;
  // (B,C) pair dword for state=lane at row tok: dword index 6 + lane (row = 70 dwords)
  const unsigned* xb = (const unsigned*)(xdbl + (size_t)b * TLEN * XP) + 6 + lane;
  float h = 0.f;
  int tl = lane & 15, qq = lane >> 4;
  for (int t0 = 0; t0 < TLEN; t0 += 16) {
#pragma unroll
    for (int t = 0; t < 16; ++t) {
      float2 q = pq[t0 + t];
      unsigned bc = xb[(size_t)(t0 + t) * (XP / 2)];
      float Bv = bflo(bc), Cv = bfhi(bc);
      h = fmaf(h, exp2f(q.x * Al2), q.y * Bv);
      ps[t * 68 + lane] = h * Cv;
    }
    float p = 0.f;
    const floatx4* pr = (const floatx4*)&ps[tl * 68 + qq * 16];
#pragma unroll
    for (int i = 0; i < 4; ++i) {
      floatx4 v = pr[i];
      p += v[0] + v[1] + v[2] + v[3];
    }
    p += __shfl_xor(p, 16);
    p += __shfl_xor(p, 32);
    if (lane < 16) {
      int t = t0 + tl;
      unsigned e = pe[t];
      py[t] = f2bf(fmaf(p, bfhi(e), bflo(e)));
    }
  }
}

// ---- transpose yT_bf[b][d][t] -> y_bf[tok][d] (bf16 -> bf16) ----
__global__ __launch_bounds__(256)
void k_t2b(const unsigned short* __restrict__ yTb, unsigned short* __restrict__ ybf) {
  int t0 = blockIdx.x * 64, d0 = blockIdx.y * 64, b = blockIdx.z;
  __shared__ unsigned short ls[64 * 66];
  int tid = threadIdx.x, j = tid & 63, w = tid >> 6;
#pragma unroll
  for (int it = 0; it < 16; ++it) {
    int dl = it * 4 + w;
    ls[dl * 66 + j] = yTb[((size_t)b * DINNER + d0 + dl) * TLEN + t0 + j];
  }
  __syncthreads();
#pragma unroll
  for (int it = 0; it < 16; ++it) {
    int tr = it * 4 + w;
    ybf[((size_t)b * TLEN + t0 + tr) * DINNER + d0 + j] = ls[j * 66 + tr];
  }
}

// ---------------- head ----------------
__global__ __launch_bounds__(256)
void k_head(const float* __restrict__ h, const float* __restrict__ hw,
            const float* __restrict__ hb, float* __restrict__ out) {
  int tok = blockIdx.x * 4 + (threadIdx.x >> 6);
  int lane = threadIdx.x & 63;
  const float* hr = h + (size_t)tok * DMODEL;
  float s = hr[lane] * hw[lane] + hr[lane + 64] * hw[lane + 64];
  if (lane < DMODEL - 128) s += hr[lane + 128] * hw[lane + 128];
#pragma unroll
  for (int off = 32; off; off >>= 1) s += __shfl_xor(s, off);
  if (lane == 0) out[tok] = s + hb[0];
}

extern "C" void kernel_launch(void* const* d_in, const int* in_sizes, int n_in,
                              void* d_out, int out_size, void* d_ws, size_t ws_size,
                              hipStream_t stream) {
  const float* x      = (const float*)d_in[0];
  const float* pre_w  = (const float*)d_in[1];
  const float* pre_b  = (const float*)d_in[2];
  const float* ln_g   = (const float*)d_in[3];
  const float* ln_b   = (const float*)d_in[4];
  const float* in_w   = (const float*)d_in[5];
  const float* conv_w = (const float*)d_in[6];
  const float* conv_b = (const float*)d_in[7];
  const float* xproj_w= (const float*)d_in[8];
  const float* dt_w   = (const float*)d_in[9];
  const float* dt_b   = (const float*)d_in[10];
  const float* A_log  = (const float*)d_in[11];
  const float* D_skip = (const float*)d_in[12];
  const float* out_w  = (const float*)d_in[13];
  const float* head_w = (const float*)d_in[14];
  const float* head_b = (const float*)d_in[15];
  float* out = (float*)d_out;

  // workspace (float units), ~198 MB:
  // h | xdbl_bf (XP rows) | qT (float2; first 5.24M f also serve as lnxd_bf/u_bf before pack)
  // | uT_bf | X (xbuf fp32 -> eT -> y_bf) | Y (zbuf_bf -> yT_bf) | wbf
  float* ws = (float*)d_ws;
  float* h    = ws;
  unsigned short* xdbl_bf = (unsigned short*)(h + (size_t)NTOK * DMODEL);
  float2* qT  = (float2*)(xdbl_bf + (size_t)NTOK * XP);
  unsigned short* uT_bf = (unsigned short*)(qT + (size_t)NTOK * DINNER);
  float* X    = (float*)(uT_bf + (size_t)NTOK * DINNER);
  float* Y    = X + (size_t)NTOK * DINNER;
  unsigned short* wbf = (unsigned short*)(Y + (size_t)NTOK * DINNER / 2);

  unsigned short* lnxd_bf = (unsigned short*)qT;   // dead before pack writes qT
  unsigned short* u_bf    = (unsigned short*)qT;   // dead before pack writes qT
  float*          xbuf    = X;
  unsigned*       eT      = (unsigned*)X;          // xbuf dead after convT
  unsigned short* y_bf    = (unsigned short*)X;    // eT dead after scan
  unsigned short* zbuf_bf = (unsigned short*)Y;
  unsigned short* yT_bf   = (unsigned short*)Y;    // zbuf dead after pack
  unsigned short* w_in    = wbf;
  unsigned short* w_xp    = wbf + 102400;
  unsigned short* w_ou    = wbf + 146560;

  k_preconv<<<NTOK * DMODEL / 256, 256, 0, stream>>>(x, pre_w, pre_b, h);

  for (int L = 0; L < NBLK; ++L) {
    k_cast<<<773, 256, 0, stream>>>(
        in_w + (size_t)L * 640 * DMODEL, xproj_w + (size_t)L * XDBL * DINNER,
        out_w + (size_t)L * DMODEL * DINNER, wbf);
    k_ln<<<NTOK / 4, 256, 0, stream>>>(h, ln_g + L * DMODEL, ln_b + L * DMODEL, lnxd_bf);
    k_mm_in<<<dim3(5, NTOK / 128), 256, 0, stream>>>(lnxd_bf, w_in, xbuf, zbuf_bf);
    k_convT<<<dim3(TLEN / 64, DINNER / 64, BATCH), 256, 0, stream>>>(
        xbuf, conv_w + (size_t)L * DINNER * DCONV, conv_b + (size_t)L * DINNER,
        uT_bf, u_bf);
    k_mm_x<<<dim3(3, NTOK / 128), 256, 0, stream>>>(u_bf, w_xp, xdbl_bf);
    k_pack<<<dim3(TLEN / 64, DINNER / 64, BATCH), 256, 0, stream>>>(
        zbuf_bf, xdbl_bf, uT_bf, dt_w + (size_t)L * DINNER * DTRANK,
        dt_b + (size_t)L * DINNER, D_skip + (size_t)L * DINNER, qT, eT);
    k_scan<<<BATCH * (DINNER / 4), 256, 0, stream>>>(
        qT, eT, xdbl_bf, A_log + (size_t)L * DINNER * DSTATE, yT_bf);
    k_t2b<<<dim3(TLEN / 64, DINNER / 64, BATCH), 256, 0, stream>>>(yT_bf, y_bf);
    k_mm_g<<<dim3(3, NTOK / 128), 256, 0, stream>>>(y_bf, w_ou, h, h, DMODEL, DINNER);
  }

  k_head<<<NTOK / 4, 256, 0, stream>>>(h, head_w, head_b, out);
}